// Round 2
// baseline (782.113 us; speedup 1.0000x reference)
//
#include <hip/hip_runtime.h>
#include <hip/hip_bf16.h>

// GAT attention scores, restructured:
//   e[edge,h] = aa[h,:F]·x[row] + aa[h,F:]·x[col]   (separable projections)
//   a = segment_softmax(leakyrelu(e), by row)       (shift-invariance: no max pass)
//
// R2: segment sums via per-XCD replicas + workgroup-scope (L2-local) fp32
// atomics instead of device-scope atomics (R1: each device atomic = 32B
// fabric transaction -> 400 MB WRITE_SIZE, 658 us).
//
// ws layout (floats): s1[N*H] | s2[N*H] | ssum[N*H] | rep[8*N*H]  = 17.6 MB

constexpr int NN = 50000;
constexpr int NE = 1600000;
constexpr int F  = 32;
constexpr int H  = 8;
constexpr int NXCD = 8;
constexpr float ALPHA = 0.2f;
constexpr float EPS   = 1e-12f;

__device__ __forceinline__ int xcc_id() {
    unsigned x;
    asm volatile("s_getreg_b32 %0, hwreg(HW_REG_XCC_ID)" : "=s"(x));
    return (int)(x & (NXCD - 1));
}

__global__ __launch_bounds__(256) void node_proj_kernel(
    const float* __restrict__ x, const float* __restrict__ aa,
    float* __restrict__ s1, float* __restrict__ s2, float* __restrict__ rep)
{
    __shared__ float aal[H * 2 * F];  // 512 floats, broadcast reads
    for (int i = threadIdx.x; i < H * 2 * F; i += 256) aal[i] = aa[i];
    __syncthreads();

    int n = blockIdx.x * 256 + threadIdx.x;
    if (n >= NN) return;

    // zero the 8 replica buffers: thread n owns rep[n*64 .. n*64+63]
    // (NN*64 == NXCD*NN*H exactly)
    {
        float4* rz = reinterpret_cast<float4*>(rep + (size_t)n * 64);
        float4 z = make_float4(0.f, 0.f, 0.f, 0.f);
#pragma unroll
        for (int i = 0; i < 16; ++i) rz[i] = z;
    }

    const float4* xp = reinterpret_cast<const float4*>(x + (size_t)n * F);
    float4 xv[F / 4];
#pragma unroll
    for (int i = 0; i < F / 4; ++i) xv[i] = xp[i];

    float o1[H], o2[H];
#pragma unroll
    for (int h = 0; h < H; ++h) {
        const float* a1 = &aal[h * 2 * F];
        const float* a2 = a1 + F;
        float acc1 = 0.f, acc2 = 0.f;
#pragma unroll
        for (int i = 0; i < F / 4; ++i) {
            acc1 = fmaf(a1[4*i+0], xv[i].x, acc1);
            acc1 = fmaf(a1[4*i+1], xv[i].y, acc1);
            acc1 = fmaf(a1[4*i+2], xv[i].z, acc1);
            acc1 = fmaf(a1[4*i+3], xv[i].w, acc1);
            acc2 = fmaf(a2[4*i+0], xv[i].x, acc2);
            acc2 = fmaf(a2[4*i+1], xv[i].y, acc2);
            acc2 = fmaf(a2[4*i+2], xv[i].z, acc2);
            acc2 = fmaf(a2[4*i+3], xv[i].w, acc2);
        }
        o1[h] = acc1; o2[h] = acc2;
    }

    float4* p1 = reinterpret_cast<float4*>(s1 + (size_t)n * H);
    float4* p2 = reinterpret_cast<float4*>(s2 + (size_t)n * H);
    p1[0] = make_float4(o1[0], o1[1], o1[2], o1[3]);
    p1[1] = make_float4(o1[4], o1[5], o1[6], o1[7]);
    p2[0] = make_float4(o2[0], o2[1], o2[2], o2[3]);
    p2[1] = make_float4(o2[4], o2[5], o2[6], o2[7]);
}

__global__ __launch_bounds__(256) void edge_sum_kernel(
    const int* __restrict__ row, const int* __restrict__ col,
    const float* __restrict__ s1, const float* __restrict__ s2,
    float* __restrict__ rep)
{
    int e = blockIdx.x * 256 + threadIdx.x;
    if (e >= NE) return;
    int r = row[e], c = col[e];

    const float4* p1 = reinterpret_cast<const float4*>(s1 + (size_t)r * H);
    const float4* p2 = reinterpret_cast<const float4*>(s2 + (size_t)c * H);
    float4 a0 = p1[0], a1 = p1[1];
    float4 b0 = p2[0], b1 = p2[1];

    float v[H] = {a0.x + b0.x, a0.y + b0.y, a0.z + b0.z, a0.w + b0.w,
                  a1.x + b1.x, a1.y + b1.y, a1.z + b1.z, a1.w + b1.w};

    // replica for this workgroup's physical XCD: atomics stay in local L2
    float* base = rep + (size_t)xcc_id() * (NN * H) + (size_t)r * H;
#pragma unroll
    for (int h = 0; h < H; ++h) {
        float t = v[h];
        t = t > 0.f ? t : ALPHA * t;
        __hip_atomic_fetch_add(base + h, __expf(t),
                               __ATOMIC_RELAXED, __HIP_MEMORY_SCOPE_WORKGROUP);
    }
}

__global__ __launch_bounds__(256) void reduce_rep_kernel(
    const float* __restrict__ rep, float* __restrict__ ssum)
{
    int i = blockIdx.x * 256 + threadIdx.x;   // over NN*H/4 float4s
    if (i >= NN * H / 4) return;
    const float4* r4 = reinterpret_cast<const float4*>(rep);
    float4 acc = r4[i];
#pragma unroll
    for (int k = 1; k < NXCD; ++k) {
        float4 t = r4[(size_t)k * (NN * H / 4) + i];
        acc.x += t.x; acc.y += t.y; acc.z += t.z; acc.w += t.w;
    }
    reinterpret_cast<float4*>(ssum)[i] = acc;
}

__global__ __launch_bounds__(256) void edge_out_kernel(
    const int* __restrict__ row, const int* __restrict__ col,
    const float* __restrict__ s1, const float* __restrict__ s2,
    const float* __restrict__ ssum, float* __restrict__ out)
{
    int e = blockIdx.x * 256 + threadIdx.x;
    if (e >= NE) return;
    int r = row[e], c = col[e];

    const float4* p1 = reinterpret_cast<const float4*>(s1 + (size_t)r * H);
    const float4* p2 = reinterpret_cast<const float4*>(s2 + (size_t)c * H);
    const float4* ps = reinterpret_cast<const float4*>(ssum + (size_t)r * H);
    float4 a0 = p1[0], a1 = p1[1];
    float4 b0 = p2[0], b1 = p2[1];
    float4 d0 = ps[0], d1 = ps[1];

    float v[H]   = {a0.x + b0.x, a0.y + b0.y, a0.z + b0.z, a0.w + b0.w,
                    a1.x + b1.x, a1.y + b1.y, a1.z + b1.z, a1.w + b1.w};
    float den[H] = {d0.x, d0.y, d0.z, d0.w, d1.x, d1.y, d1.z, d1.w};

#pragma unroll
    for (int h = 0; h < H; ++h) {
        float t = v[h];
        t = t > 0.f ? t : ALPHA * t;
        float ex = __expf(t);                    // identical recompute to edge_sum
        out[(size_t)h * NE + e] = ex / (den[h] + EPS);  // coalesced per head
    }
}

extern "C" void kernel_launch(void* const* d_in, const int* in_sizes, int n_in,
                              void* d_out, int out_size, void* d_ws, size_t ws_size,
                              hipStream_t stream) {
    const float* x   = (const float*)d_in[0];
    const float* aa  = (const float*)d_in[1];
    const int*   row = (const int*)d_in[2];
    const int*   col = (const int*)d_in[3];
    float* out = (float*)d_out;

    float* s1   = (float*)d_ws;
    float* s2   = s1 + (size_t)NN * H;
    float* ssum = s2 + (size_t)NN * H;
    float* rep  = ssum + (size_t)NN * H;   // 8 * NN * H floats

    node_proj_kernel<<<(NN + 255) / 256, 256, 0, stream>>>(x, aa, s1, s2, rep);
    edge_sum_kernel<<<NE / 256, 256, 0, stream>>>(row, col, s1, s2, rep);
    reduce_rep_kernel<<<(NN * H / 4 + 255) / 256, 256, 0, stream>>>(rep, ssum);
    edge_out_kernel<<<NE / 256, 256, 0, stream>>>(row, col, s1, s2, ssum, out);
}

// Round 3
// 345.441 us; speedup vs baseline: 2.2641x; 2.2641x over previous
//
#include <hip/hip_runtime.h>
#include <hip/hip_bf16.h>

// GAT attention scores, restructured:
//   e[edge,h] = aa[h,:F]·x[row] + aa[h,F:]·x[col]   (separable projections)
//   a = segment_softmax(leakyrelu(e), by row)       (shift-invariance: no max pass)
//
// R3: global fp32 atomics are write-through on gfx950 (32 B HBM transaction
// each; R1/R2 measured WRITE_SIZE == 32B x 12.8M, ~20 G/s). Replace the
// scatter-atomic segment sum with node-range-partitioned LDS accumulation:
// block owns (node range x edge stripe), accumulates in LDS via ds_add_f32,
// dumps per-stripe partials with plain stores; tiny reduce folds stripes.
//
// ws layout (floats): s1[N*H] | s2[N*H] | ssum[N*H] | partial[S][N*H] = 17.6 MB

constexpr int NN = 50000;
constexpr int NE = 1600000;
constexpr int F  = 32;
constexpr int H  = 8;
constexpr float ALPHA = 0.2f;
constexpr float EPS   = 1e-12f;

constexpr int RNODES  = 2048;                       // nodes per range (64 KB LDS acc)
constexpr int NRANGES = (NN + RNODES - 1) / RNODES; // 25
constexpr int NSTRIPE = 8;                          // edge stripes
constexpr int SLEN    = NE / NSTRIPE;               // 200000

__global__ __launch_bounds__(256) void node_proj_kernel(
    const float* __restrict__ x, const float* __restrict__ aa,
    float* __restrict__ s1, float* __restrict__ s2)
{
    __shared__ float aal[H * 2 * F];  // 512 floats, broadcast reads
    for (int i = threadIdx.x; i < H * 2 * F; i += 256) aal[i] = aa[i];
    __syncthreads();

    int n = blockIdx.x * 256 + threadIdx.x;
    if (n >= NN) return;

    const float4* xp = reinterpret_cast<const float4*>(x + (size_t)n * F);
    float4 xv[F / 4];
#pragma unroll
    for (int i = 0; i < F / 4; ++i) xv[i] = xp[i];

    float o1[H], o2[H];
#pragma unroll
    for (int h = 0; h < H; ++h) {
        const float* a1 = &aal[h * 2 * F];
        const float* a2 = a1 + F;
        float acc1 = 0.f, acc2 = 0.f;
#pragma unroll
        for (int i = 0; i < F / 4; ++i) {
            acc1 = fmaf(a1[4*i+0], xv[i].x, acc1);
            acc1 = fmaf(a1[4*i+1], xv[i].y, acc1);
            acc1 = fmaf(a1[4*i+2], xv[i].z, acc1);
            acc1 = fmaf(a1[4*i+3], xv[i].w, acc1);
            acc2 = fmaf(a2[4*i+0], xv[i].x, acc2);
            acc2 = fmaf(a2[4*i+1], xv[i].y, acc2);
            acc2 = fmaf(a2[4*i+2], xv[i].z, acc2);
            acc2 = fmaf(a2[4*i+3], xv[i].w, acc2);
        }
        o1[h] = acc1; o2[h] = acc2;
    }

    float4* p1 = reinterpret_cast<float4*>(s1 + (size_t)n * H);
    float4* p2 = reinterpret_cast<float4*>(s2 + (size_t)n * H);
    p1[0] = make_float4(o1[0], o1[1], o1[2], o1[3]);
    p1[1] = make_float4(o1[4], o1[5], o1[6], o1[7]);
    p2[0] = make_float4(o2[0], o2[1], o2[2], o2[3]);
    p2[1] = make_float4(o2[4], o2[5], o2[6], o2[7]);
}

// grid: (NRANGES, NSTRIPE), block: 1024. LDS acc tile + ds_add_f32, no global atomics.
__global__ __launch_bounds__(1024) void edge_range_sum_kernel(
    const int* __restrict__ row, const int* __restrict__ col,
    const float* __restrict__ s1, const float* __restrict__ s2,
    float* __restrict__ partial)
{
    __shared__ float acc[RNODES * H];  // 64 KB

    const int range_base = blockIdx.x * RNODES;
    const int sbeg = blockIdx.y * SLEN;
    const int send = sbeg + SLEN;

    for (int i = threadIdx.x; i < RNODES * H; i += 1024) acc[i] = 0.f;
    __syncthreads();

    for (int e = sbeg + threadIdx.x; e < send; e += 1024) {
        int r = row[e];
        unsigned d = (unsigned)(r - range_base);
        if (d < (unsigned)RNODES) {
            int c = col[e];
            const float4* p1 = reinterpret_cast<const float4*>(s1 + (size_t)r * H);
            const float4* p2 = reinterpret_cast<const float4*>(s2 + (size_t)c * H);
            float4 a0 = p1[0], a1 = p1[1];
            float4 b0 = p2[0], b1 = p2[1];
            float v[H] = {a0.x + b0.x, a0.y + b0.y, a0.z + b0.z, a0.w + b0.w,
                          a1.x + b1.x, a1.y + b1.y, a1.z + b1.z, a1.w + b1.w};
            float* ap = &acc[d * H];
#pragma unroll
            for (int h = 0; h < H; ++h) {
                float t = v[h];
                t = fmaxf(t, ALPHA * t);          // leakyrelu (alpha<1)
                atomicAdd(ap + h, __expf(t));     // ds_add_f32
            }
        }
    }
    __syncthreads();

    // dump tile -> partial[stripe][node][h], clipped to NN
    const int count = min(RNODES, NN - range_base);  // last range: 848
    if (count <= 0) return;
    const float4* acc4 = reinterpret_cast<const float4*>(acc);
    float4* out4 = reinterpret_cast<float4*>(partial) +
                   ((size_t)blockIdx.y * NN + range_base) * (H / 4);
    for (int j = threadIdx.x; j < count * (H / 4); j += 1024) out4[j] = acc4[j];
}

__global__ __launch_bounds__(256) void reduce_partial_kernel(
    const float* __restrict__ partial, float* __restrict__ ssum)
{
    int i = blockIdx.x * 256 + threadIdx.x;   // over NN*H/4 float4s
    if (i >= NN * H / 4) return;
    const float4* p4 = reinterpret_cast<const float4*>(partial);
    float4 acc = p4[i];
#pragma unroll
    for (int s = 1; s < NSTRIPE; ++s) {
        float4 t = p4[(size_t)s * (NN * H / 4) + i];
        acc.x += t.x; acc.y += t.y; acc.z += t.z; acc.w += t.w;
    }
    reinterpret_cast<float4*>(ssum)[i] = acc;
}

__global__ __launch_bounds__(256) void edge_out_kernel(
    const int* __restrict__ row, const int* __restrict__ col,
    const float* __restrict__ s1, const float* __restrict__ s2,
    const float* __restrict__ ssum, float* __restrict__ out)
{
    int e = blockIdx.x * 256 + threadIdx.x;
    if (e >= NE) return;
    int r = row[e], c = col[e];

    const float4* p1 = reinterpret_cast<const float4*>(s1 + (size_t)r * H);
    const float4* p2 = reinterpret_cast<const float4*>(s2 + (size_t)c * H);
    const float4* ps = reinterpret_cast<const float4*>(ssum + (size_t)r * H);
    float4 a0 = p1[0], a1 = p1[1];
    float4 b0 = p2[0], b1 = p2[1];
    float4 d0 = ps[0], d1 = ps[1];

    float v[H]   = {a0.x + b0.x, a0.y + b0.y, a0.z + b0.z, a0.w + b0.w,
                    a1.x + b1.x, a1.y + b1.y, a1.z + b1.z, a1.w + b1.w};
    float den[H] = {d0.x, d0.y, d0.z, d0.w, d1.x, d1.y, d1.z, d1.w};

#pragma unroll
    for (int h = 0; h < H; ++h) {
        float t = v[h];
        t = fmaxf(t, ALPHA * t);
        float ex = __expf(t);                    // identical recompute to sum pass
        out[(size_t)h * NE + e] = ex / (den[h] + EPS);  // coalesced per head
    }
}

extern "C" void kernel_launch(void* const* d_in, const int* in_sizes, int n_in,
                              void* d_out, int out_size, void* d_ws, size_t ws_size,
                              hipStream_t stream) {
    const float* x   = (const float*)d_in[0];
    const float* aa  = (const float*)d_in[1];
    const int*   row = (const int*)d_in[2];
    const int*   col = (const int*)d_in[3];
    float* out = (float*)d_out;

    float* s1      = (float*)d_ws;
    float* s2      = s1 + (size_t)NN * H;
    float* ssum    = s2 + (size_t)NN * H;
    float* partial = ssum + (size_t)NN * H;   // NSTRIPE * NN * H floats

    node_proj_kernel<<<(NN + 255) / 256, 256, 0, stream>>>(x, aa, s1, s2);
    edge_range_sum_kernel<<<dim3(NRANGES, NSTRIPE), 1024, 0, stream>>>(row, col, s1, s2, partial);
    reduce_partial_kernel<<<(NN * H / 4 + 255) / 256, 256, 0, stream>>>(partial, ssum);
    edge_out_kernel<<<NE / 256, 256, 0, stream>>>(row, col, s1, s2, ssum, out);
}

// Round 4
// 259.289 us; speedup vs baseline: 3.0164x; 1.3323x over previous
//
#include <hip/hip_runtime.h>
#include <hip/hip_bf16.h>

// GAT attention scores:
//   e[edge,h] = aa[h,:F]·x[row] + aa[h,F:]·x[col]   (separable projections)
//   a = segment_softmax(leakyrelu(e), by row)       (shift-invariance: no max pass)
//
// R4: counting-sort edges into 98 node-ranges (512 nodes each), then the LDS
// segment sum runs dense (100% lane occupancy, 1 visit/edge) instead of R3's
// 25x redundant scan at 4% lane density. LDS acc addresses swizzled (h+d)&7
// to spread ds_add banks. edge_out processes 4 edges/thread, float4 I/O.
//
// ws (floats): s1[400k] s2[400k] ssum[400k] partial[4*400k] binned[1.6M u32]
//              counts[39200] block_base[39200] rstart[99]  ~= 17.9 MB

constexpr int NN = 50000;
constexpr int NE = 1600000;
constexpr int F  = 32;
constexpr int H  = 8;
constexpr float ALPHA = 0.2f;
constexpr float EPS   = 1e-12f;

constexpr int RSH     = 9;
constexpr int RNODES  = 1 << RSH;                   // 512 nodes/range -> 16 KB acc
constexpr int NR      = (NN + RNODES - 1) / RNODES; // 98 ranges
constexpr int NB      = 400;                        // blocks in bin passes
constexpr int CHUNK   = NE / NB;                    // 4000 edges/block
constexpr int SC      = 4;                          // stripes in range_sum

__global__ __launch_bounds__(256) void node_proj_kernel(
    const float* __restrict__ x, const float* __restrict__ aa,
    float* __restrict__ s1, float* __restrict__ s2)
{
    __shared__ float aal[H * 2 * F];
    for (int i = threadIdx.x; i < H * 2 * F; i += 256) aal[i] = aa[i];
    __syncthreads();

    int n = blockIdx.x * 256 + threadIdx.x;
    if (n >= NN) return;

    const float4* xp = reinterpret_cast<const float4*>(x + (size_t)n * F);
    float4 xv[F / 4];
#pragma unroll
    for (int i = 0; i < F / 4; ++i) xv[i] = xp[i];

    float o1[H], o2[H];
#pragma unroll
    for (int h = 0; h < H; ++h) {
        const float* a1 = &aal[h * 2 * F];
        const float* a2 = a1 + F;
        float acc1 = 0.f, acc2 = 0.f;
#pragma unroll
        for (int i = 0; i < F / 4; ++i) {
            acc1 = fmaf(a1[4*i+0], xv[i].x, acc1);
            acc1 = fmaf(a1[4*i+1], xv[i].y, acc1);
            acc1 = fmaf(a1[4*i+2], xv[i].z, acc1);
            acc1 = fmaf(a1[4*i+3], xv[i].w, acc1);
            acc2 = fmaf(a2[4*i+0], xv[i].x, acc2);
            acc2 = fmaf(a2[4*i+1], xv[i].y, acc2);
            acc2 = fmaf(a2[4*i+2], xv[i].z, acc2);
            acc2 = fmaf(a2[4*i+3], xv[i].w, acc2);
        }
        o1[h] = acc1; o2[h] = acc2;
    }

    float4* p1 = reinterpret_cast<float4*>(s1 + (size_t)n * H);
    float4* p2 = reinterpret_cast<float4*>(s2 + (size_t)n * H);
    p1[0] = make_float4(o1[0], o1[1], o1[2], o1[3]);
    p1[1] = make_float4(o1[4], o1[5], o1[6], o1[7]);
    p2[0] = make_float4(o2[0], o2[1], o2[2], o2[3]);
    p2[1] = make_float4(o2[4], o2[5], o2[6], o2[7]);
}

__global__ __launch_bounds__(256) void bin_count_kernel(
    const int* __restrict__ row, int* __restrict__ counts)
{
    __shared__ int cnt[NR];
    for (int i = threadIdx.x; i < NR; i += 256) cnt[i] = 0;
    __syncthreads();
    const int base = blockIdx.x * CHUNK;
    for (int i = threadIdx.x; i < CHUNK; i += 256)
        atomicAdd(&cnt[row[base + i] >> RSH], 1);
    __syncthreads();
    for (int i = threadIdx.x; i < NR; i += 256)
        counts[i * NB + blockIdx.x] = cnt[i];
}

// one block: per-(range,block) exclusive scatter bases + range starts
__global__ __launch_bounds__(128) void scan_kernel(
    const int* __restrict__ counts, int* __restrict__ block_base,
    int* __restrict__ rstart)
{
    __shared__ int rs[NR + 1];
    const int t = threadIdx.x;
    __shared__ int tot[NR];
    if (t < NR) {
        const int4* c4 = reinterpret_cast<const int4*>(counts + t * NB);
        int s = 0;
        for (int b = 0; b < NB / 4; ++b) {
            int4 v = c4[b];
            s += v.x + v.y + v.z + v.w;
        }
        tot[t] = s;
    }
    __syncthreads();
    if (t == 0) {
        int run = 0;
        for (int r = 0; r < NR; ++r) { rs[r] = run; run += tot[r]; }
        rs[NR] = run;
    }
    __syncthreads();
    if (t < NR) {
        const int4* c4 = reinterpret_cast<const int4*>(counts + t * NB);
        int4* b4 = reinterpret_cast<int4*>(block_base + t * NB);
        int run = rs[t];
        for (int b = 0; b < NB / 4; ++b) {
            int4 v = c4[b];
            int4 o;
            o.x = run; run += v.x;
            o.y = run; run += v.y;
            o.z = run; run += v.z;
            o.w = run; run += v.w;
            b4[b] = o;
        }
    }
    if (t <= NR) rstart[t] = rs[t];
}

__global__ __launch_bounds__(256) void bin_scatter_kernel(
    const int* __restrict__ row, const int* __restrict__ col,
    const int* __restrict__ block_base, unsigned* __restrict__ binned)
{
    __shared__ int cur[NR];
    for (int i = threadIdx.x; i < NR; i += 256)
        cur[i] = block_base[i * NB + blockIdx.x];
    __syncthreads();
    const int base = blockIdx.x * CHUNK;
    for (int i = threadIdx.x; i < CHUNK; i += 256) {
        int r = row[base + i], c = col[base + i];
        int pos = atomicAdd(&cur[r >> RSH], 1);
        binned[pos] = ((unsigned)r << 16) | (unsigned)c;   // both < 65536
    }
}

// grid (NR, SC): dense per-range LDS segment sum, no global atomics
__global__ __launch_bounds__(256) void range_sum_kernel(
    const unsigned* __restrict__ binned, const int* __restrict__ rstart,
    const float* __restrict__ s1, const float* __restrict__ s2,
    float* __restrict__ partial)
{
    __shared__ float acc[RNODES * H];  // 16 KB
    for (int i = threadIdx.x; i < RNODES * H; i += 256) acc[i] = 0.f;
    __syncthreads();

    const int rx = blockIdx.x;
    const int beg = rstart[rx], end = rstart[rx + 1];
    const int rbase = rx << RSH;

    for (int i = beg + blockIdx.y * 256 + threadIdx.x; i < end; i += SC * 256) {
        unsigned v = binned[i];
        int r = (int)(v >> 16), c = (int)(v & 0xFFFFu);
        const float4* p1 = reinterpret_cast<const float4*>(s1 + (size_t)r * H);
        const float4* p2 = reinterpret_cast<const float4*>(s2 + (size_t)c * H);
        float4 a0 = p1[0], a1 = p1[1];
        float4 b0 = p2[0], b1 = p2[1];
        float vv[H] = {a0.x + b0.x, a0.y + b0.y, a0.z + b0.z, a0.w + b0.w,
                       a1.x + b1.x, a1.y + b1.y, a1.z + b1.z, a1.w + b1.w};
        int d = r - rbase;
        float* ap = &acc[d << 3];
#pragma unroll
        for (int h = 0; h < H; ++h) {
            float t = vv[h];
            t = fmaxf(t, ALPHA * t);
            atomicAdd(ap + ((h + d) & 7), __expf(t));  // swizzled bank spread
        }
    }
    __syncthreads();

    const int count = min(RNODES, NN - rbase);
    float* outp = partial + ((size_t)blockIdx.y * NN + rbase) * H;
    for (int j = threadIdx.x; j < count * H; j += 256) {
        int d = j >> 3, h = j & 7;
        outp[j] = acc[(d << 3) + ((h + d) & 7)];       // unswizzle
    }
}

__global__ __launch_bounds__(256) void reduce4_kernel(
    const float* __restrict__ partial, float* __restrict__ ssum)
{
    int i = blockIdx.x * 256 + threadIdx.x;   // over NN*H/4 float4s
    if (i >= NN * H / 4) return;
    const float4* p4 = reinterpret_cast<const float4*>(partial);
    float4 acc = p4[i];
#pragma unroll
    for (int s = 1; s < SC; ++s) {
        float4 t = p4[(size_t)s * (NN * H / 4) + i];
        acc.x += t.x; acc.y += t.y; acc.z += t.z; acc.w += t.w;
    }
    reinterpret_cast<float4*>(ssum)[i] = acc;
}

// 4 edges/thread, float4 loads + per-head float4 stores
__global__ __launch_bounds__(256) void edge_out_kernel(
    const int* __restrict__ row, const int* __restrict__ col,
    const float* __restrict__ s1, const float* __restrict__ s2,
    const float* __restrict__ ssum, float* __restrict__ out)
{
    int e0 = (blockIdx.x * 256 + threadIdx.x) * 4;
    if (e0 >= NE) return;
    int4 r4 = *reinterpret_cast<const int4*>(row + e0);
    int4 c4 = *reinterpret_cast<const int4*>(col + e0);
    int rr[4] = {r4.x, r4.y, r4.z, r4.w};
    int cc[4] = {c4.x, c4.y, c4.z, c4.w};

    float res[4][H];
#pragma unroll
    for (int k = 0; k < 4; ++k) {
        const float4* p1 = reinterpret_cast<const float4*>(s1 + (size_t)rr[k] * H);
        const float4* p2 = reinterpret_cast<const float4*>(s2 + (size_t)cc[k] * H);
        const float4* ps = reinterpret_cast<const float4*>(ssum + (size_t)rr[k] * H);
        float4 a0 = p1[0], a1 = p1[1];
        float4 b0 = p2[0], b1 = p2[1];
        float4 d0 = ps[0], d1 = ps[1];
        float vv[H]  = {a0.x + b0.x, a0.y + b0.y, a0.z + b0.z, a0.w + b0.w,
                        a1.x + b1.x, a1.y + b1.y, a1.z + b1.z, a1.w + b1.w};
        float den[H] = {d0.x, d0.y, d0.z, d0.w, d1.x, d1.y, d1.z, d1.w};
#pragma unroll
        for (int h = 0; h < H; ++h) {
            float t = vv[h];
            t = fmaxf(t, ALPHA * t);
            res[k][h] = __expf(t) / (den[h] + EPS);  // exp identical to sum pass
        }
    }
#pragma unroll
    for (int h = 0; h < H; ++h) {
        *reinterpret_cast<float4*>(out + (size_t)h * NE + e0) =
            make_float4(res[0][h], res[1][h], res[2][h], res[3][h]);
    }
}

extern "C" void kernel_launch(void* const* d_in, const int* in_sizes, int n_in,
                              void* d_out, int out_size, void* d_ws, size_t ws_size,
                              hipStream_t stream) {
    const float* x   = (const float*)d_in[0];
    const float* aa  = (const float*)d_in[1];
    const int*   row = (const int*)d_in[2];
    const int*   col = (const int*)d_in[3];
    float* out = (float*)d_out;

    float* s1      = (float*)d_ws;
    float* s2      = s1 + (size_t)NN * H;
    float* ssum    = s2 + (size_t)NN * H;
    float* partial = ssum + (size_t)NN * H;              // SC * NN * H
    unsigned* binned = (unsigned*)(partial + (size_t)SC * NN * H);
    int* counts     = (int*)(binned + NE);
    int* block_base = counts + NR * NB;
    int* rstart     = block_base + NR * NB;

    node_proj_kernel<<<(NN + 255) / 256, 256, 0, stream>>>(x, aa, s1, s2);
    bin_count_kernel<<<NB, 256, 0, stream>>>(row, counts);
    scan_kernel<<<1, 128, 0, stream>>>(counts, block_base, rstart);
    bin_scatter_kernel<<<NB, 256, 0, stream>>>(row, col, block_base, binned);
    range_sum_kernel<<<dim3(NR, SC), 256, 0, stream>>>(binned, rstart, s1, s2, partial);
    reduce4_kernel<<<(NN * H / 4 + 255) / 256, 256, 0, stream>>>(partial, ssum);
    edge_out_kernel<<<(NE / 4 + 255) / 256, 256, 0, stream>>>(row, col, s1, s2, ssum, out);
}